// Round 2
// baseline (685.029 us; speedup 1.0000x reference)
//
#include <hip/hip_runtime.h>
#include <hip/hip_bf16.h>

#define EDGES  500000
#define NNODES 100000
#define QN     256
#define RN     401
#define DD     64
#define AA     64
#define OO     64

// ---------------------------------------------------------------------------
// K1: Xs[n,a] = sum_d hidden[n,d] * Ws_W[a,d]    (one wave per node)
// ---------------------------------------------------------------------------
__global__ void k_xs(const float* __restrict__ hidden,
                     const float* __restrict__ Ws_W,
                     float* __restrict__ Xs) {
    __shared__ float WsT[DD][AA + 1];   // WsT[d][a] = Ws[a][d]
    int tid = threadIdx.x;
    for (int idx = tid; idx < AA * DD; idx += blockDim.x) {
        int a = idx >> 6, d = idx & 63;
        WsT[d][a] = Ws_W[idx];
    }
    __syncthreads();
    int wave = tid >> 6, lane = tid & 63;
    int node = blockIdx.x * (blockDim.x >> 6) + wave;
    if (node >= NNODES) return;
    float hv = hidden[(size_t)node * DD + lane];   // lane d holds h[d]
    float acc = 0.f;
#pragma unroll
    for (int d = 0; d < DD; ++d) {
        float h = __shfl(hv, d, 64);    // broadcast h[d]
        acc += h * WsT[d][lane];        // lane = a
    }
    Xs[(size_t)node * AA + lane] = acc;
}

// ---------------------------------------------------------------------------
// K2: P[q,r,a] = Ws_b[a] + Wr.hr + Wq.hq + Wqr.(hq*hr)   (one wave per (q,r))
// ---------------------------------------------------------------------------
__global__ void k_p(const float* __restrict__ q_emb,
                    const float* __restrict__ rela,
                    const float* __restrict__ Wq_W,
                    const float* __restrict__ Wr_W,
                    const float* __restrict__ Wqr_W,
                    const float* __restrict__ Ws_b,
                    float* __restrict__ P) {
    __shared__ float WqT[DD][AA + 1];
    __shared__ float WrT[DD][AA + 1];
    __shared__ float WqrT[DD][AA + 1];
    int tid = threadIdx.x;
    for (int idx = tid; idx < AA * DD; idx += blockDim.x) {
        int a = idx >> 6, d = idx & 63;
        WqT[d][a]  = Wq_W[idx];
        WrT[d][a]  = Wr_W[idx];
        WqrT[d][a] = Wqr_W[idx];
    }
    __syncthreads();
    int wave = tid >> 6, lane = tid & 63;
    int pair = blockIdx.x * (blockDim.x >> 6) + wave;
    if (pair >= QN * RN) return;
    int q = pair / RN;
    int r = pair - q * RN;
    float hq = q_emb[(size_t)q * DD + lane];
    float hr = rela[(size_t)r * DD + lane];
    float acc = Ws_b[lane];
#pragma unroll
    for (int d = 0; d < DD; ++d) {
        float hqd = __shfl(hq, d, 64);
        float hrd = __shfl(hr, d, 64);
        acc += hqd * WqT[d][lane] + hrd * WrT[d][lane] + hqd * hrd * WqrT[d][lane];
    }
    P[(size_t)pair * AA + lane] = acc;
}

// ---------------------------------------------------------------------------
// K3: per-edge alpha + scatter-add of message    (one wave per edge)
// ---------------------------------------------------------------------------
__global__ void k_edge(const int* __restrict__ edges,
                       const float* __restrict__ Xs,
                       const float* __restrict__ P,
                       const float* __restrict__ hidden,
                       const float* __restrict__ rela,
                       const float* __restrict__ wa_W,
                       const float* __restrict__ wa_b,
                       float* __restrict__ agg,
                       float* __restrict__ alpha_out) {
    int tid = threadIdx.x;
    int wave = tid >> 6, lane = tid & 63;
    int e = blockIdx.x * (blockDim.x >> 6) + wave;
    if (e >= EDGES) return;
    const int* ep = edges + (size_t)e * 6;
    int q   = ep[0];
    int r   = ep[2];
    int sub = ep[4];
    int obj = ep[5];
    float pre = Xs[(size_t)sub * AA + lane] + P[((size_t)q * RN + r) * AA + lane];
    float v = fmaxf(pre, 0.f) * wa_W[lane];
#pragma unroll
    for (int off = 32; off > 0; off >>= 1) v += __shfl_xor(v, off, 64);
    float alpha = 1.f / (1.f + __expf(-(v + wa_b[0])));
    if (lane == 0) alpha_out[e] = alpha;
    float m = alpha * hidden[(size_t)sub * DD + lane] * rela[(size_t)r * DD + lane];
    atomicAdd(&agg[(size_t)obj * DD + lane], m);
}

// ---------------------------------------------------------------------------
// K4: hidden_new[n,o] = sum_d agg[n,d] * Wh_W[o,d]   (one wave per node)
// ---------------------------------------------------------------------------
__global__ void k_out(const float* __restrict__ agg,
                      const float* __restrict__ Wh_W,
                      float* __restrict__ out) {
    __shared__ float WhT[DD][OO + 1];
    int tid = threadIdx.x;
    for (int idx = tid; idx < OO * DD; idx += blockDim.x) {
        int o = idx >> 6, d = idx & 63;
        WhT[d][o] = Wh_W[idx];
    }
    __syncthreads();
    int wave = tid >> 6, lane = tid & 63;
    int node = blockIdx.x * (blockDim.x >> 6) + wave;
    if (node >= NNODES) return;
    float av = agg[(size_t)node * DD + lane];
    float acc = 0.f;
#pragma unroll
    for (int d = 0; d < DD; ++d) acc += __shfl(av, d, 64) * WhT[d][lane];
    out[(size_t)node * OO + lane] = acc;
}

// ---------------------------------------------------------------------------
extern "C" void kernel_launch(void* const* d_in, const int* in_sizes, int n_in,
                              void* d_out, int out_size, void* d_ws, size_t ws_size,
                              hipStream_t stream) {
    const float* q_emb  = (const float*)d_in[1];
    const float* rela   = (const float*)d_in[2];
    const float* hidden = (const float*)d_in[3];
    const int*   edges  = (const int*)d_in[4];
    const float* Ws_W   = (const float*)d_in[6];
    const float* Ws_b   = (const float*)d_in[7];
    const float* Wr_W   = (const float*)d_in[8];
    const float* Wq_W   = (const float*)d_in[9];
    const float* Wqr_W  = (const float*)d_in[10];
    const float* wa_W   = (const float*)d_in[11];
    const float* wa_b   = (const float*)d_in[12];
    const float* Wh_W   = (const float*)d_in[13];

    float* Xs  = (float*)d_ws;                          // N*A   = 6,400,000 floats
    float* P   = Xs + (size_t)NNODES * AA;              // Q*R*A = 6,569,984 floats
    float* agg = P + (size_t)QN * RN * AA;              // N*D   = 6,400,000 floats

    float* out       = (float*)d_out;                   // hidden_new (N*O)
    float* alpha_out = out + (size_t)NNODES * OO;       // alpha (E)

    hipMemsetAsync(agg, 0, (size_t)NNODES * DD * sizeof(float), stream);

    k_xs<<<(NNODES + 3) / 4, 256, 0, stream>>>(hidden, Ws_W, Xs);
    k_p <<<(QN * RN + 3) / 4, 256, 0, stream>>>(q_emb, rela, Wq_W, Wr_W, Wqr_W, Ws_b, P);
    k_edge<<<(EDGES + 3) / 4, 256, 0, stream>>>(edges, Xs, P, hidden, rela, wa_W, wa_b,
                                                agg, alpha_out);
    k_out<<<(NNODES + 3) / 4, 256, 0, stream>>>(agg, Wh_W, out);
}

// Round 3
// 278.953 us; speedup vs baseline: 2.4557x; 2.4557x over previous
//
#include <hip/hip_runtime.h>
#include <hip/hip_bf16.h>

#define EDGES  500000
#define NNODES 100000
#define QN     256
#define RN     401
#define DD     64
#define AA     64
#define OO     64

typedef __attribute__((ext_vector_type(8))) short short8;
typedef __attribute__((ext_vector_type(4))) float f32x4;

__device__ inline unsigned short f2bf(float f) {
    union { float f; unsigned int u; } v; v.f = f;
    unsigned int u = v.u;
    u += 0x7FFFu + ((u >> 16) & 1u);   // round-to-nearest-even
    return (unsigned short)(u >> 16);
}

__device__ inline short8 load8_cvt(const float* __restrict__ p) {
    f32x4 x0 = ((const f32x4*)p)[0];
    f32x4 x1 = ((const f32x4*)p)[1];
    short8 r;
    r[0] = (short)f2bf(x0[0]); r[1] = (short)f2bf(x0[1]);
    r[2] = (short)f2bf(x0[2]); r[3] = (short)f2bf(x0[3]);
    r[4] = (short)f2bf(x1[0]); r[5] = (short)f2bf(x1[1]);
    r[6] = (short)f2bf(x1[2]); r[7] = (short)f2bf(x1[3]);
    return r;
}

__device__ inline short8 load8_cvt_prod(const float* __restrict__ pa,
                                        const float* __restrict__ pb) {
    f32x4 a0 = ((const f32x4*)pa)[0];
    f32x4 a1 = ((const f32x4*)pa)[1];
    f32x4 b0 = ((const f32x4*)pb)[0];
    f32x4 b1 = ((const f32x4*)pb)[1];
    short8 r;
    r[0] = (short)f2bf(a0[0]*b0[0]); r[1] = (short)f2bf(a0[1]*b0[1]);
    r[2] = (short)f2bf(a0[2]*b0[2]); r[3] = (short)f2bf(a0[3]*b0[3]);
    r[4] = (short)f2bf(a1[0]*b1[0]); r[5] = (short)f2bf(a1[1]*b1[1]);
    r[6] = (short)f2bf(a1[2]*b1[2]); r[7] = (short)f2bf(a1[3]*b1[3]);
    return r;
}

// ---------------------------------------------------------------------------
// K1: Xs = hidden @ Ws^T   (MFMA, K=64). Block=256 (4 waves), 64 rows/block.
// ---------------------------------------------------------------------------
__global__ void k_xs(const float* __restrict__ hidden,
                     const float* __restrict__ Ws_W,
                     float* __restrict__ Xs) {
    __shared__ short W[AA * 72];            // row a: 64 k + 8 pad (stride 144 B)
    int tid = threadIdx.x;
    for (int idx = tid; idx < AA * DD; idx += 256) {
        int a = idx >> 6, d = idx & 63;
        W[a * 72 + d] = (short)f2bf(Ws_W[idx]);
    }
    __syncthreads();
    int wave = tid >> 6, lane = tid & 63;
    int quad = lane >> 4, l15 = lane & 15;
    int rowbase = blockIdx.x * 64 + wave * 16;
    int row_a = rowbase + l15;              // A-fragment row

    f32x4 acc[4];
    for (int t = 0; t < 4; ++t) { acc[t][0]=acc[t][1]=acc[t][2]=acc[t][3]=0.f; }

#pragma unroll
    for (int ks = 0; ks < 2; ++ks) {
        int ka = ks * 32 + quad * 8;
        short8 afrag;
        if (row_a < NNODES) afrag = load8_cvt(hidden + (size_t)row_a * DD + ka);
        else                afrag = short8{0,0,0,0,0,0,0,0};
#pragma unroll
        for (int t = 0; t < 4; ++t) {
            short8 bfrag = *(const short8*)&W[(t * 16 + l15) * 72 + ka];
            acc[t] = __builtin_amdgcn_mfma_f32_16x16x32_bf16(afrag, bfrag, acc[t], 0, 0, 0);
        }
    }
#pragma unroll
    for (int t = 0; t < 4; ++t)
#pragma unroll
        for (int r = 0; r < 4; ++r) {
            int row = rowbase + quad * 4 + r;
            if (row < NNODES) Xs[(size_t)row * AA + t * 16 + l15] = acc[t][r];
        }
}

// ---------------------------------------------------------------------------
// K2: P[q*RN+r, a] = Ws_b + concat(hq,hr,hq*hr) @ concat(Wq,Wr,Wqr)^T  (K=192)
// Block=256 (4 waves), 64 pairs/block; grid = 102656/64 = 1604 exact.
// ---------------------------------------------------------------------------
__global__ void k_p(const float* __restrict__ q_emb,
                    const float* __restrict__ rela,
                    const float* __restrict__ Wq_W,
                    const float* __restrict__ Wr_W,
                    const float* __restrict__ Wqr_W,
                    const float* __restrict__ Ws_b,
                    float* __restrict__ P) {
    __shared__ short W[AA * 200];           // row a: 192 k + 8 pad (stride 400 B)
    int tid = threadIdx.x;
    for (int idx = tid; idx < AA * 192; idx += 256) {
        int a = idx / 192, k = idx - a * 192;
        float v = (k < 64) ? Wq_W[a * 64 + k]
                : (k < 128) ? Wr_W[a * 64 + (k - 64)]
                            : Wqr_W[a * 64 + (k - 128)];
        W[a * 200 + k] = (short)f2bf(v);
    }
    __syncthreads();
    int wave = tid >> 6, lane = tid & 63;
    int quad = lane >> 4, l15 = lane & 15;
    int pairbase = blockIdx.x * 64 + wave * 16;
    int mypair = pairbase + l15;
    int q = mypair / RN;
    int r = mypair - q * RN;
    const float* hq = q_emb + (size_t)q * DD;
    const float* hr = rela  + (size_t)r * DD;

    float bias = Ws_b[l15];                 // placeholder; fixed per n-tile below
    f32x4 acc[4];
#pragma unroll
    for (int t = 0; t < 4; ++t) {
        float b = Ws_b[t * 16 + l15];
        acc[t][0] = acc[t][1] = acc[t][2] = acc[t][3] = b;
    }
    (void)bias;

#pragma unroll
    for (int ks = 0; ks < 6; ++ks) {
        int ka = ks * 32 + quad * 8;        // 0..191, 8-chunks never straddle segments
        short8 afrag;
        if (ka < 64)       afrag = load8_cvt(hq + ka);
        else if (ka < 128) afrag = load8_cvt(hr + (ka - 64));
        else               afrag = load8_cvt_prod(hq + (ka - 128), hr + (ka - 128));
#pragma unroll
        for (int t = 0; t < 4; ++t) {
            short8 bfrag = *(const short8*)&W[(t * 16 + l15) * 200 + ka];
            acc[t] = __builtin_amdgcn_mfma_f32_16x16x32_bf16(afrag, bfrag, acc[t], 0, 0, 0);
        }
    }
#pragma unroll
    for (int t = 0; t < 4; ++t)
#pragma unroll
        for (int rg = 0; rg < 4; ++rg) {
            int row = pairbase + quad * 4 + rg;
            P[(size_t)row * AA + t * 16 + l15] = acc[t][rg];
        }
}

// ---------------------------------------------------------------------------
// K3: per-edge alpha + scatter-add of message    (one wave per edge)
// ---------------------------------------------------------------------------
__global__ void k_edge(const int* __restrict__ edges,
                       const float* __restrict__ Xs,
                       const float* __restrict__ P,
                       const float* __restrict__ hidden,
                       const float* __restrict__ rela,
                       const float* __restrict__ wa_W,
                       const float* __restrict__ wa_b,
                       float* __restrict__ agg,
                       float* __restrict__ alpha_out) {
    int tid = threadIdx.x;
    int wave = tid >> 6, lane = tid & 63;
    int e = blockIdx.x * (blockDim.x >> 6) + wave;
    if (e >= EDGES) return;
    const int* ep = edges + (size_t)e * 6;
    int q   = ep[0];
    int r   = ep[2];
    int sub = ep[4];
    int obj = ep[5];
    float pre = Xs[(size_t)sub * AA + lane] + P[((size_t)q * RN + r) * AA + lane];
    float v = fmaxf(pre, 0.f) * wa_W[lane];
#pragma unroll
    for (int off = 32; off > 0; off >>= 1) v += __shfl_xor(v, off, 64);
    float alpha = 1.f / (1.f + __expf(-(v + wa_b[0])));
    if (lane == 0) alpha_out[e] = alpha;
    float m = alpha * hidden[(size_t)sub * DD + lane] * rela[(size_t)r * DD + lane];
    atomicAdd(&agg[(size_t)obj * DD + lane], m);
}

// ---------------------------------------------------------------------------
// K4: hidden_new = agg @ Wh^T   (MFMA, K=64)
// ---------------------------------------------------------------------------
__global__ void k_out(const float* __restrict__ agg,
                      const float* __restrict__ Wh_W,
                      float* __restrict__ out) {
    __shared__ short W[OO * 72];
    int tid = threadIdx.x;
    for (int idx = tid; idx < OO * DD; idx += 256) {
        int o = idx >> 6, d = idx & 63;
        W[o * 72 + d] = (short)f2bf(Wh_W[idx]);
    }
    __syncthreads();
    int wave = tid >> 6, lane = tid & 63;
    int quad = lane >> 4, l15 = lane & 15;
    int rowbase = blockIdx.x * 64 + wave * 16;
    int row_a = rowbase + l15;

    f32x4 acc[4];
    for (int t = 0; t < 4; ++t) { acc[t][0]=acc[t][1]=acc[t][2]=acc[t][3]=0.f; }

#pragma unroll
    for (int ks = 0; ks < 2; ++ks) {
        int ka = ks * 32 + quad * 8;
        short8 afrag;
        if (row_a < NNODES) afrag = load8_cvt(agg + (size_t)row_a * DD + ka);
        else                afrag = short8{0,0,0,0,0,0,0,0};
#pragma unroll
        for (int t = 0; t < 4; ++t) {
            short8 bfrag = *(const short8*)&W[(t * 16 + l15) * 72 + ka];
            acc[t] = __builtin_amdgcn_mfma_f32_16x16x32_bf16(afrag, bfrag, acc[t], 0, 0, 0);
        }
    }
#pragma unroll
    for (int t = 0; t < 4; ++t)
#pragma unroll
        for (int r = 0; r < 4; ++r) {
            int row = rowbase + quad * 4 + r;
            if (row < NNODES) out[(size_t)row * OO + t * 16 + l15] = acc[t][r];
        }
}

// ---------------------------------------------------------------------------
extern "C" void kernel_launch(void* const* d_in, const int* in_sizes, int n_in,
                              void* d_out, int out_size, void* d_ws, size_t ws_size,
                              hipStream_t stream) {
    const float* q_emb  = (const float*)d_in[1];
    const float* rela   = (const float*)d_in[2];
    const float* hidden = (const float*)d_in[3];
    const int*   edges  = (const int*)d_in[4];
    const float* Ws_W   = (const float*)d_in[6];
    const float* Ws_b   = (const float*)d_in[7];
    const float* Wr_W   = (const float*)d_in[8];
    const float* Wq_W   = (const float*)d_in[9];
    const float* Wqr_W  = (const float*)d_in[10];
    const float* wa_W   = (const float*)d_in[11];
    const float* wa_b   = (const float*)d_in[12];
    const float* Wh_W   = (const float*)d_in[13];

    float* Xs  = (float*)d_ws;                          // N*A   = 6,400,000 floats
    float* P   = Xs + (size_t)NNODES * AA;              // Q*R*A = 6,569,984 floats
    float* agg = P + (size_t)QN * RN * AA;              // N*D   = 6,400,000 floats

    float* out       = (float*)d_out;                   // hidden_new (N*O)
    float* alpha_out = out + (size_t)NNODES * OO;       // alpha (E)

    hipMemsetAsync(agg, 0, (size_t)NNODES * DD * sizeof(float), stream);

    k_xs<<<(NNODES + 63) / 64, 256, 0, stream>>>(hidden, Ws_W, Xs);
    k_p <<<(QN * RN) / 64, 256, 0, stream>>>(q_emb, rela, Wq_W, Wr_W, Wqr_W, Ws_b, P);
    k_edge<<<(EDGES + 3) / 4, 256, 0, stream>>>(edges, Xs, P, hidden, rela, wa_W, wa_b,
                                                agg, alpha_out);
    k_out<<<(NNODES + 63) / 64, 256, 0, stream>>>(agg, Wh_W, out);
}

// Round 5
// 223.093 us; speedup vs baseline: 3.0706x; 1.2504x over previous
//
#include <hip/hip_runtime.h>
#include <hip/hip_bf16.h>

#define EDGES  500000
#define NNODES 100000
#define QN     256
#define RN     401
#define DD     64
#define AA     64
#define OO     64

typedef __attribute__((ext_vector_type(8))) short short8;
typedef __attribute__((ext_vector_type(2))) short short2v;
typedef __attribute__((ext_vector_type(4))) float f32x4;
typedef __attribute__((ext_vector_type(2))) float f32x2;

__device__ inline unsigned short f2bf(float f) {
    union { float f; unsigned int u; } v; v.f = f;
    unsigned int u = v.u;
    u += 0x7FFFu + ((u >> 16) & 1u);   // round-to-nearest-even
    return (unsigned short)(u >> 16);
}

__device__ inline short8 load8_cvt(const float* __restrict__ p) {
    f32x4 x0 = ((const f32x4*)p)[0];
    f32x4 x1 = ((const f32x4*)p)[1];
    short8 r;
    r[0] = (short)f2bf(x0[0]); r[1] = (short)f2bf(x0[1]);
    r[2] = (short)f2bf(x0[2]); r[3] = (short)f2bf(x0[3]);
    r[4] = (short)f2bf(x1[0]); r[5] = (short)f2bf(x1[1]);
    r[6] = (short)f2bf(x1[2]); r[7] = (short)f2bf(x1[3]);
    return r;
}

__device__ inline short8 load8_cvt_prod(const float* __restrict__ pa,
                                        const float* __restrict__ pb) {
    f32x4 a0 = ((const f32x4*)pa)[0];
    f32x4 a1 = ((const f32x4*)pa)[1];
    f32x4 b0 = ((const f32x4*)pb)[0];
    f32x4 b1 = ((const f32x4*)pb)[1];
    short8 r;
    r[0] = (short)f2bf(a0[0]*b0[0]); r[1] = (short)f2bf(a0[1]*b0[1]);
    r[2] = (short)f2bf(a0[2]*b0[2]); r[3] = (short)f2bf(a0[3]*b0[3]);
    r[4] = (short)f2bf(a1[0]*b1[0]); r[5] = (short)f2bf(a1[1]*b1[1]);
    r[6] = (short)f2bf(a1[2]*b1[2]); r[7] = (short)f2bf(a1[3]*b1[3]);
    return r;
}

// packed bf16x2 atomic add (global_atomic_pk_add_bf16, gfx90a+/CDNA4)
__device__ inline void atomic_pk_add_bf16(short* addr, short2v v) {
#if __has_builtin(__builtin_amdgcn_global_atomic_fadd_v2bf16)
    __builtin_amdgcn_global_atomic_fadd_v2bf16(
        (__attribute__((address_space(1))) short2v*)addr, v);
#else
    asm volatile("global_atomic_pk_add_bf16 %0, %1, off"
                 :: "v"(addr), "v"(v) : "memory");
#endif
}

// ---------------------------------------------------------------------------
// K1: Xs = hidden @ Ws^T   (MFMA, K=64). Block=256 (4 waves), 64 rows/block.
// ---------------------------------------------------------------------------
__global__ void k_xs(const float* __restrict__ hidden,
                     const float* __restrict__ Ws_W,
                     float* __restrict__ Xs) {
    __shared__ short W[AA * 72];            // row a: 64 k + 8 pad
    int tid = threadIdx.x;
    for (int idx = tid; idx < AA * DD; idx += 256) {
        int a = idx >> 6, d = idx & 63;
        W[a * 72 + d] = (short)f2bf(Ws_W[idx]);
    }
    __syncthreads();
    int wave = tid >> 6, lane = tid & 63;
    int quad = lane >> 4, l15 = lane & 15;
    int rowbase = blockIdx.x * 64 + wave * 16;
    int row_a = rowbase + l15;

    f32x4 acc[4];
    for (int t = 0; t < 4; ++t) { acc[t][0]=acc[t][1]=acc[t][2]=acc[t][3]=0.f; }

#pragma unroll
    for (int ks = 0; ks < 2; ++ks) {
        int ka = ks * 32 + quad * 8;
        short8 afrag;
        if (row_a < NNODES) afrag = load8_cvt(hidden + (size_t)row_a * DD + ka);
        else                afrag = short8{0,0,0,0,0,0,0,0};
#pragma unroll
        for (int t = 0; t < 4; ++t) {
            short8 bfrag = *(const short8*)&W[(t * 16 + l15) * 72 + ka];
            acc[t] = __builtin_amdgcn_mfma_f32_16x16x32_bf16(afrag, bfrag, acc[t], 0, 0, 0);
        }
    }
#pragma unroll
    for (int t = 0; t < 4; ++t)
#pragma unroll
        for (int r = 0; r < 4; ++r) {
            int row = rowbase + quad * 4 + r;
            if (row < NNODES) Xs[(size_t)row * AA + t * 16 + l15] = acc[t][r];
        }
}

// ---------------------------------------------------------------------------
// K2: P = Ws_b + concat(hq,hr,hq*hr) @ concat(Wq,Wr,Wqr)^T  (K=192)
// ---------------------------------------------------------------------------
__global__ void k_p(const float* __restrict__ q_emb,
                    const float* __restrict__ rela,
                    const float* __restrict__ Wq_W,
                    const float* __restrict__ Wr_W,
                    const float* __restrict__ Wqr_W,
                    const float* __restrict__ Ws_b,
                    float* __restrict__ P) {
    __shared__ short W[AA * 200];           // row a: 192 k + 8 pad
    int tid = threadIdx.x;
    for (int idx = tid; idx < AA * 192; idx += 256) {
        int a = idx / 192, k = idx - a * 192;
        float v = (k < 64) ? Wq_W[a * 64 + k]
                : (k < 128) ? Wr_W[a * 64 + (k - 64)]
                            : Wqr_W[a * 64 + (k - 128)];
        W[a * 200 + k] = (short)f2bf(v);
    }
    __syncthreads();
    int wave = tid >> 6, lane = tid & 63;
    int quad = lane >> 4, l15 = lane & 15;
    int pairbase = blockIdx.x * 64 + wave * 16;
    int mypair = pairbase + l15;
    int q = mypair / RN;
    int r = mypair - q * RN;
    const float* hq = q_emb + (size_t)q * DD;
    const float* hr = rela  + (size_t)r * DD;

    f32x4 acc[4];
#pragma unroll
    for (int t = 0; t < 4; ++t) {
        float b = Ws_b[t * 16 + l15];
        acc[t][0] = acc[t][1] = acc[t][2] = acc[t][3] = b;
    }

#pragma unroll
    for (int ks = 0; ks < 6; ++ks) {
        int ka = ks * 32 + quad * 8;
        short8 afrag;
        if (ka < 64)       afrag = load8_cvt(hq + ka);
        else if (ka < 128) afrag = load8_cvt(hr + (ka - 64));
        else               afrag = load8_cvt_prod(hq + (ka - 128), hr + (ka - 128));
#pragma unroll
        for (int t = 0; t < 4; ++t) {
            short8 bfrag = *(const short8*)&W[(t * 16 + l15) * 200 + ka];
            acc[t] = __builtin_amdgcn_mfma_f32_16x16x32_bf16(afrag, bfrag, acc[t], 0, 0, 0);
        }
    }
#pragma unroll
    for (int t = 0; t < 4; ++t)
#pragma unroll
        for (int rg = 0; rg < 4; ++rg) {
            int row = pairbase + quad * 4 + rg;
            P[(size_t)row * AA + t * 16 + l15] = acc[t][rg];
        }
}

// ---------------------------------------------------------------------------
// K3: 2 edges per wave (32 lanes / edge, float2 per lane), bf16 pk atomics.
// 500000 edges = 62500 blocks * 8 edges, exact (no tail).
// ---------------------------------------------------------------------------
__global__ void k_edge(const int* __restrict__ edges,
                       const float* __restrict__ Xs,
                       const float* __restrict__ P,
                       const float* __restrict__ hidden,
                       const float* __restrict__ rela,
                       const float* __restrict__ wa_W,
                       const float* __restrict__ wa_b,
                       short* __restrict__ agg,
                       float* __restrict__ alpha_out) {
    int tid  = threadIdx.x;
    int wave = tid >> 6, lane = tid & 63;
    int l32  = lane & 31;                    // lane within half-wave
    int half = lane >> 5;
    size_t e = (size_t)blockIdx.x * 8 + wave * 2 + half;

    const int* ep = edges + e * 6;
    int q = ep[0];
    int r = ep[2];
    int2 so = *(const int2*)&ep[4];          // {sub, obj}
    int sub = so.x, obj = so.y;

    int c2 = 2 * l32;                        // column pair handled by this lane
    f32x2 xs = *(const f32x2*)&Xs[(size_t)sub * AA + c2];
    f32x2 pp = *(const f32x2*)&P[((size_t)q * RN + r) * AA + c2];
    f32x2 wa = *(const f32x2*)&wa_W[c2];

    float v = fmaxf(xs[0] + pp[0], 0.f) * wa[0]
            + fmaxf(xs[1] + pp[1], 0.f) * wa[1];
#pragma unroll
    for (int off = 16; off > 0; off >>= 1) v += __shfl_xor(v, off, 64); // stays in half
    float alpha = 1.f / (1.f + __expf(-(v + wa_b[0])));
    if (l32 == 0) alpha_out[e] = alpha;

    f32x2 hs = *(const f32x2*)&hidden[(size_t)sub * DD + c2];
    f32x2 hr = *(const f32x2*)&rela[(size_t)r * DD + c2];
    short2v m;
    m[0] = (short)f2bf(alpha * hs[0] * hr[0]);
    m[1] = (short)f2bf(alpha * hs[1] * hr[1]);
    atomic_pk_add_bf16(agg + (size_t)obj * DD + c2, m);
}

// ---------------------------------------------------------------------------
// K4: hidden_new = agg @ Wh^T   (MFMA, K=64; agg already bf16)
// ---------------------------------------------------------------------------
__global__ void k_out(const short* __restrict__ agg,
                      const float* __restrict__ Wh_W,
                      float* __restrict__ out) {
    __shared__ short W[OO * 72];
    int tid = threadIdx.x;
    for (int idx = tid; idx < OO * DD; idx += 256) {
        int o = idx >> 6, d = idx & 63;
        W[o * 72 + d] = (short)f2bf(Wh_W[idx]);
    }
    __syncthreads();
    int wave = tid >> 6, lane = tid & 63;
    int quad = lane >> 4, l15 = lane & 15;
    int rowbase = blockIdx.x * 64 + wave * 16;
    int row_a = rowbase + l15;

    f32x4 acc[4];
    for (int t = 0; t < 4; ++t) { acc[t][0]=acc[t][1]=acc[t][2]=acc[t][3]=0.f; }

#pragma unroll
    for (int ks = 0; ks < 2; ++ks) {
        int ka = ks * 32 + quad * 8;
        short8 afrag;
        if (row_a < NNODES) afrag = *(const short8*)(agg + (size_t)row_a * DD + ka);
        else                afrag = short8{0,0,0,0,0,0,0,0};
#pragma unroll
        for (int t = 0; t < 4; ++t) {
            short8 bfrag = *(const short8*)&W[(t * 16 + l15) * 72 + ka];
            acc[t] = __builtin_amdgcn_mfma_f32_16x16x32_bf16(afrag, bfrag, acc[t], 0, 0, 0);
        }
    }
#pragma unroll
    for (int t = 0; t < 4; ++t)
#pragma unroll
        for (int r = 0; r < 4; ++r) {
            int row = rowbase + quad * 4 + r;
            if (row < NNODES) out[(size_t)row * OO + t * 16 + l15] = acc[t][r];
        }
}

// ---------------------------------------------------------------------------
extern "C" void kernel_launch(void* const* d_in, const int* in_sizes, int n_in,
                              void* d_out, int out_size, void* d_ws, size_t ws_size,
                              hipStream_t stream) {
    const float* q_emb  = (const float*)d_in[1];
    const float* rela   = (const float*)d_in[2];
    const float* hidden = (const float*)d_in[3];
    const int*   edges  = (const int*)d_in[4];
    const float* Ws_W   = (const float*)d_in[6];
    const float* Ws_b   = (const float*)d_in[7];
    const float* Wr_W   = (const float*)d_in[8];
    const float* Wq_W   = (const float*)d_in[9];
    const float* Wqr_W  = (const float*)d_in[10];
    const float* wa_W   = (const float*)d_in[11];
    const float* wa_b   = (const float*)d_in[12];
    const float* Wh_W   = (const float*)d_in[13];

    float* Xs  = (float*)d_ws;                          // N*A   floats
    float* P   = Xs + (size_t)NNODES * AA;              // Q*R*A floats
    short* agg = (short*)(P + (size_t)QN * RN * AA);    // N*D   bf16

    float* out       = (float*)d_out;                   // hidden_new (N*O)
    float* alpha_out = out + (size_t)NNODES * OO;       // alpha (E)

    (void)hipMemsetAsync(agg, 0, (size_t)NNODES * DD * sizeof(short), stream);

    k_xs<<<(NNODES + 63) / 64, 256, 0, stream>>>(hidden, Ws_W, Xs);
    k_p <<<(QN * RN) / 64, 256, 0, stream>>>(q_emb, rela, Wq_W, Wr_W, Wqr_W, Ws_b, P);
    k_edge<<<EDGES / 8, 256, 0, stream>>>(edges, Xs, P, hidden, rela, wa_W, wa_b,
                                          agg, alpha_out);
    k_out<<<(NNODES + 63) / 64, 256, 0, stream>>>(agg, Wh_W, out);
}

// Round 6
// 213.786 us; speedup vs baseline: 3.2043x; 1.0435x over previous
//
#include <hip/hip_runtime.h>
#include <hip/hip_bf16.h>

#define EDGES  500000
#define NNODES 100000
#define QN     256
#define RN     401
#define DD     64
#define AA     64
#define OO     64

typedef __attribute__((ext_vector_type(8))) short short8;
typedef __attribute__((ext_vector_type(2))) short short2v;
typedef __attribute__((ext_vector_type(4))) float f32x4;
typedef __attribute__((ext_vector_type(2))) float f32x2;

__device__ inline unsigned short f2bf(float f) {
    union { float f; unsigned int u; } v; v.f = f;
    unsigned int u = v.u;
    u += 0x7FFFu + ((u >> 16) & 1u);   // round-to-nearest-even
    return (unsigned short)(u >> 16);
}

// unpack two bf16 (packed in a u32, little-endian) to two fp32
__device__ inline f32x2 bfpair2f(unsigned int u) {
    union { unsigned int i; float f; } lo, hi;
    lo.i = u << 16;
    hi.i = u & 0xFFFF0000u;
    f32x2 r; r[0] = lo.f; r[1] = hi.f; return r;
}

__device__ inline short8 load8_cvt(const float* __restrict__ p) {
    f32x4 x0 = ((const f32x4*)p)[0];
    f32x4 x1 = ((const f32x4*)p)[1];
    short8 r;
    r[0] = (short)f2bf(x0[0]); r[1] = (short)f2bf(x0[1]);
    r[2] = (short)f2bf(x0[2]); r[3] = (short)f2bf(x0[3]);
    r[4] = (short)f2bf(x1[0]); r[5] = (short)f2bf(x1[1]);
    r[6] = (short)f2bf(x1[2]); r[7] = (short)f2bf(x1[3]);
    return r;
}

__device__ inline short8 load8_cvt_prod(const float* __restrict__ pa,
                                        const float* __restrict__ pb) {
    f32x4 a0 = ((const f32x4*)pa)[0];
    f32x4 a1 = ((const f32x4*)pa)[1];
    f32x4 b0 = ((const f32x4*)pb)[0];
    f32x4 b1 = ((const f32x4*)pb)[1];
    short8 r;
    r[0] = (short)f2bf(a0[0]*b0[0]); r[1] = (short)f2bf(a0[1]*b0[1]);
    r[2] = (short)f2bf(a0[2]*b0[2]); r[3] = (short)f2bf(a0[3]*b0[3]);
    r[4] = (short)f2bf(a1[0]*b1[0]); r[5] = (short)f2bf(a1[1]*b1[1]);
    r[6] = (short)f2bf(a1[2]*b1[2]); r[7] = (short)f2bf(a1[3]*b1[3]);
    return r;
}

// packed bf16x2 atomic add (global_atomic_pk_add_bf16, gfx90a+/CDNA4)
__device__ inline void atomic_pk_add_bf16(short* addr, short2v v) {
#if __has_builtin(__builtin_amdgcn_global_atomic_fadd_v2bf16)
    __builtin_amdgcn_global_atomic_fadd_v2bf16(
        (__attribute__((address_space(1))) short2v*)addr, v);
#else
    asm volatile("global_atomic_pk_add_bf16 %0, %1, off"
                 :: "v"(addr), "v"(v) : "memory");
#endif
}

// ---------------------------------------------------------------------------
// K1: Xs = hidden @ Ws^T (MFMA, K=64), bf16 out; also emits hidden_bf (bf16
// copy of hidden) for the edge kernel — the fragments are already converted.
// ---------------------------------------------------------------------------
__global__ void k_xs(const float* __restrict__ hidden,
                     const float* __restrict__ Ws_W,
                     short* __restrict__ Xs,
                     short* __restrict__ hidden_bf) {
    __shared__ short W[AA * 72];            // row a: 64 k + 8 pad
    int tid = threadIdx.x;
    for (int idx = tid; idx < AA * DD; idx += 256) {
        int a = idx >> 6, d = idx & 63;
        W[a * 72 + d] = (short)f2bf(Ws_W[idx]);
    }
    __syncthreads();
    int wave = tid >> 6, lane = tid & 63;
    int quad = lane >> 4, l15 = lane & 15;
    int rowbase = blockIdx.x * 64 + wave * 16;
    int row_a = rowbase + l15;

    f32x4 acc[4];
    for (int t = 0; t < 4; ++t) { acc[t][0]=acc[t][1]=acc[t][2]=acc[t][3]=0.f; }

#pragma unroll
    for (int ks = 0; ks < 2; ++ks) {
        int ka = ks * 32 + quad * 8;
        short8 afrag;
        if (row_a < NNODES) {
            afrag = load8_cvt(hidden + (size_t)row_a * DD + ka);
            *(short8*)(hidden_bf + (size_t)row_a * DD + ka) = afrag;  // free bf16 copy
        } else {
            afrag = short8{0,0,0,0,0,0,0,0};
        }
#pragma unroll
        for (int t = 0; t < 4; ++t) {
            short8 bfrag = *(const short8*)&W[(t * 16 + l15) * 72 + ka];
            acc[t] = __builtin_amdgcn_mfma_f32_16x16x32_bf16(afrag, bfrag, acc[t], 0, 0, 0);
        }
    }
#pragma unroll
    for (int t = 0; t < 4; ++t)
#pragma unroll
        for (int r = 0; r < 4; ++r) {
            int row = rowbase + quad * 4 + r;
            if (row < NNODES) Xs[(size_t)row * AA + t * 16 + l15] = (short)f2bf(acc[t][r]);
        }
}

// ---------------------------------------------------------------------------
// K2: P = Ws_b + concat(hq,hr,hq*hr) @ concat(Wq,Wr,Wqr)^T  (K=192), bf16 out
// ---------------------------------------------------------------------------
__global__ void k_p(const float* __restrict__ q_emb,
                    const float* __restrict__ rela,
                    const float* __restrict__ Wq_W,
                    const float* __restrict__ Wr_W,
                    const float* __restrict__ Wqr_W,
                    const float* __restrict__ Ws_b,
                    short* __restrict__ P) {
    __shared__ short W[AA * 200];           // row a: 192 k + 8 pad
    int tid = threadIdx.x;
    for (int idx = tid; idx < AA * 192; idx += 256) {
        int a = idx / 192, k = idx - a * 192;
        float v = (k < 64) ? Wq_W[a * 64 + k]
                : (k < 128) ? Wr_W[a * 64 + (k - 64)]
                            : Wqr_W[a * 64 + (k - 128)];
        W[a * 200 + k] = (short)f2bf(v);
    }
    __syncthreads();
    int wave = tid >> 6, lane = tid & 63;
    int quad = lane >> 4, l15 = lane & 15;
    int pairbase = blockIdx.x * 64 + wave * 16;
    int mypair = pairbase + l15;
    int q = mypair / RN;
    int r = mypair - q * RN;
    const float* hq = q_emb + (size_t)q * DD;
    const float* hr = rela  + (size_t)r * DD;

    f32x4 acc[4];
#pragma unroll
    for (int t = 0; t < 4; ++t) {
        float b = Ws_b[t * 16 + l15];
        acc[t][0] = acc[t][1] = acc[t][2] = acc[t][3] = b;
    }

#pragma unroll
    for (int ks = 0; ks < 6; ++ks) {
        int ka = ks * 32 + quad * 8;
        short8 afrag;
        if (ka < 64)       afrag = load8_cvt(hq + ka);
        else if (ka < 128) afrag = load8_cvt(hr + (ka - 64));
        else               afrag = load8_cvt_prod(hq + (ka - 128), hr + (ka - 128));
#pragma unroll
        for (int t = 0; t < 4; ++t) {
            short8 bfrag = *(const short8*)&W[(t * 16 + l15) * 200 + ka];
            acc[t] = __builtin_amdgcn_mfma_f32_16x16x32_bf16(afrag, bfrag, acc[t], 0, 0, 0);
        }
    }
#pragma unroll
    for (int t = 0; t < 4; ++t)
#pragma unroll
        for (int rg = 0; rg < 4; ++rg) {
            int row = pairbase + quad * 4 + rg;
            P[(size_t)row * AA + t * 16 + l15] = (short)f2bf(acc[t][rg]);
        }
}

// ---------------------------------------------------------------------------
// K3: 2 edges per wave (32 lanes / edge, bf16x2 per lane), bf16 pk atomics.
// All gathered rows are bf16 → 128 B = 1 cacheline per row.
// ---------------------------------------------------------------------------
__global__ void k_edge(const int* __restrict__ edges,
                       const short* __restrict__ Xs,
                       const short* __restrict__ P,
                       const short* __restrict__ hidden_bf,
                       const float* __restrict__ rela,
                       const float* __restrict__ wa_W,
                       const float* __restrict__ wa_b,
                       short* __restrict__ agg,
                       float* __restrict__ alpha_out) {
    int tid  = threadIdx.x;
    int wave = tid >> 6, lane = tid & 63;
    int l32  = lane & 31;                    // lane within half-wave
    int half = lane >> 5;
    size_t e = (size_t)blockIdx.x * 8 + wave * 2 + half;

    const int* ep = edges + e * 6;
    int q = ep[0];
    int r = ep[2];
    int2 so = *(const int2*)&ep[4];          // {sub, obj}
    int sub = so.x, obj = so.y;

    int c2 = 2 * l32;                        // column pair handled by this lane
    unsigned int xs_u = *(const unsigned int*)&Xs[(size_t)sub * AA + c2];
    unsigned int pp_u = *(const unsigned int*)&P[((size_t)q * RN + r) * AA + c2];
    f32x2 xs = bfpair2f(xs_u);
    f32x2 pp = bfpair2f(pp_u);
    f32x2 wa = *(const f32x2*)&wa_W[c2];

    float v = fmaxf(xs[0] + pp[0], 0.f) * wa[0]
            + fmaxf(xs[1] + pp[1], 0.f) * wa[1];
#pragma unroll
    for (int off = 16; off > 0; off >>= 1) v += __shfl_xor(v, off, 64); // stays in half
    float alpha = 1.f / (1.f + __expf(-(v + wa_b[0])));
    if (l32 == 0) alpha_out[e] = alpha;

    unsigned int hs_u = *(const unsigned int*)&hidden_bf[(size_t)sub * DD + c2];
    f32x2 hs = bfpair2f(hs_u);
    f32x2 hr = *(const f32x2*)&rela[(size_t)r * DD + c2];
    short2v m;
    m[0] = (short)f2bf(alpha * hs[0] * hr[0]);
    m[1] = (short)f2bf(alpha * hs[1] * hr[1]);
    atomic_pk_add_bf16((short*)agg + (size_t)obj * DD + c2, m);
}

// ---------------------------------------------------------------------------
// K4: hidden_new = agg @ Wh^T   (MFMA, K=64; agg already bf16)
// ---------------------------------------------------------------------------
__global__ void k_out(const short* __restrict__ agg,
                      const float* __restrict__ Wh_W,
                      float* __restrict__ out) {
    __shared__ short W[OO * 72];
    int tid = threadIdx.x;
    for (int idx = tid; idx < OO * DD; idx += 256) {
        int o = idx >> 6, d = idx & 63;
        W[o * 72 + d] = (short)f2bf(Wh_W[idx]);
    }
    __syncthreads();
    int wave = tid >> 6, lane = tid & 63;
    int quad = lane >> 4, l15 = lane & 15;
    int rowbase = blockIdx.x * 64 + wave * 16;
    int row_a = rowbase + l15;

    f32x4 acc[4];
    for (int t = 0; t < 4; ++t) { acc[t][0]=acc[t][1]=acc[t][2]=acc[t][3]=0.f; }

#pragma unroll
    for (int ks = 0; ks < 2; ++ks) {
        int ka = ks * 32 + quad * 8;
        short8 afrag;
        if (row_a < NNODES) afrag = *(const short8*)(agg + (size_t)row_a * DD + ka);
        else                afrag = short8{0,0,0,0,0,0,0,0};
#pragma unroll
        for (int t = 0; t < 4; ++t) {
            short8 bfrag = *(const short8*)&W[(t * 16 + l15) * 72 + ka];
            acc[t] = __builtin_amdgcn_mfma_f32_16x16x32_bf16(afrag, bfrag, acc[t], 0, 0, 0);
        }
    }
#pragma unroll
    for (int t = 0; t < 4; ++t)
#pragma unroll
        for (int r = 0; r < 4; ++r) {
            int row = rowbase + quad * 4 + r;
            if (row < NNODES) out[(size_t)row * OO + t * 16 + l15] = acc[t][r];
        }
}

// ---------------------------------------------------------------------------
extern "C" void kernel_launch(void* const* d_in, const int* in_sizes, int n_in,
                              void* d_out, int out_size, void* d_ws, size_t ws_size,
                              hipStream_t stream) {
    const float* q_emb  = (const float*)d_in[1];
    const float* rela   = (const float*)d_in[2];
    const float* hidden = (const float*)d_in[3];
    const int*   edges  = (const int*)d_in[4];
    const float* Ws_W   = (const float*)d_in[6];
    const float* Ws_b   = (const float*)d_in[7];
    const float* Wr_W   = (const float*)d_in[8];
    const float* Wq_W   = (const float*)d_in[9];
    const float* Wqr_W  = (const float*)d_in[10];
    const float* wa_W   = (const float*)d_in[11];
    const float* wa_b   = (const float*)d_in[12];
    const float* Wh_W   = (const float*)d_in[13];

    // workspace layout (all bf16 shorts, element counts):
    short* Xs        = (short*)d_ws;                         // N*A
    short* P         = Xs + (size_t)NNODES * AA;             // Q*R*A
    short* hidden_bf = P + (size_t)QN * RN * AA;             // N*D
    short* agg       = hidden_bf + (size_t)NNODES * DD;      // N*D

    float* out       = (float*)d_out;                        // hidden_new (N*O)
    float* alpha_out = out + (size_t)NNODES * OO;            // alpha (E)

    (void)hipMemsetAsync(agg, 0, (size_t)NNODES * DD * sizeof(short), stream);

    k_xs<<<(NNODES + 63) / 64, 256, 0, stream>>>(hidden, Ws_W, Xs, hidden_bf);
    k_p <<<(QN * RN) / 64, 256, 0, stream>>>(q_emb, rela, Wq_W, Wr_W, Wqr_W, Ws_b, P);
    k_edge<<<EDGES / 8, 256, 0, stream>>>(edges, Xs, P, hidden_bf, rela, wa_W, wa_b,
                                          agg, alpha_out);
    k_out<<<(NNODES + 63) / 64, 256, 0, stream>>>(agg, Wh_W, out);
}